// Round 7
// baseline (265.884 us; speedup 1.0000x reference)
//
#include <hip/hip_runtime.h>
#include <stdint.h>

typedef unsigned short u16;
typedef __bf16 bf16x8 __attribute__((ext_vector_type(8)));
typedef float f32x4 __attribute__((ext_vector_type(4)));

__device__ __forceinline__ u16 f2bf(float f) {
  union { float f; uint32_t u; } x; x.f = f;
  uint32_t u = x.u;
  u += 0x7fffu + ((u >> 16) & 1u);   // round-to-nearest-even
  return (u16)(u >> 16);
}
__device__ __forceinline__ float bf2f(uint32_t lo16) {
  union { uint32_t u; float f; } x; x.u = lo16 << 16; return x.f;
}

__device__ __forceinline__ void async_load16(const u16* g, u16* l) {
  __builtin_amdgcn_global_load_lds(
      (const __attribute__((address_space(1))) void*)g,
      (__attribute__((address_space(3))) void*)l,
      16, 0, 0);
}

// ---------------- prep_w: sigmoid(beta) + weight converts (x handled in gemm1) --------
__global__ __launch_bounds__(256) void prep_w(const float* __restrict__ Wq,
                                              const float* __restrict__ Wfc,
                                              const float* __restrict__ braw,
                                              u16* __restrict__ wqb,
                                              u16* __restrict__ wfcb,
                                              float* __restrict__ beta) {
  int gid = blockIdx.x * 256 + threadIdx.x;  // [0, 131072)
  if (gid < 1024) beta[gid] = 1.0f / (1.0f + expf(-braw[gid]));
  const int HH = 1024 * 1024;
  int i = gid * 16;
  const float* src = (i < HH) ? (Wq + i) : (Wfc + (i - HH));
  u16* dst = (i < HH) ? (wqb + i) : (wfcb + (i - HH));
#pragma unroll
  for (int c = 0; c < 4; c++) {
    float4 v = *(const float4*)(src + c * 4);
    ushort4 o = {f2bf(v.x), f2bf(v.y), f2bf(v.z), f2bf(v.w)};
    *(ushort4*)(dst + c * 4) = o;
  }
}

// ---------------- GEMM: C = A * B^T + bias ----------------
// 128x128 tile, BK=64 (16 K-iters), 4 waves (2x2), each wave 64x64 via 4x4
// mfma_f32_16x16x32_bf16, two 32-k sub-steps/iter. XOR-8 LDS swizzle keeps
// ds_read_b128 conflict-free. EXPLICIT s_waitcnt(0) before the post-staging
// barrier (r3 raced without it; r4/r6 validated the explicit drain).
// AF32=1 (gemm1): A staged directly from fp32 with in-register convert —
// eliminates the separate 96 MB x-conversion pass. B stays on async
// global_load_lds (wave-uniform dest + lane*16).
template <int RELU, int OUTBF, int AF32>
__global__ __launch_bounds__(256) void gemm_bt(const void* __restrict__ Araw,
                                               const u16* __restrict__ B,
                                               const float* __restrict__ bias,
                                               void* __restrict__ Cout,
                                               int M, int N, int K) {
  __shared__ u16 As[128 * 64];
  __shared__ u16 Bs[128 * 64];

  const int tid  = threadIdx.x;
  const int lane = tid & 63;

  // XCD-aware remap (grid = 1024 = 128 m-tiles x 8 n-tiles; xcd = L % 8):
  // XCD c owns m-tiles [16c,16c+16) x all 8 n-tiles -> ~3 MB L2 working set.
  const int L  = blockIdx.x;
  const int xc = L & 7;
  const int k8 = L >> 3;
  const int tile_n = (k8 & 7) * 128;
  const int tile_m = ((xc << 4) | (k8 >> 3)) * 128;

  const int wm = ((tid >> 7) & 1) * 64;
  const int wn = ((tid >> 6) & 1) * 64;

  // B staging (async): per issue, 256 threads cover 32 rows x 8 chunks(16B).
  // row = tid>>3, dest chunk = tid&7, source chunk = (tid&7) ^ (row&7).
  const int srow   = tid >> 3;
  const int schunk = (tid & 7) ^ ((tid >> 3) & 7);
  u16* ldsB = &Bs[((tid >> 6) * 8) * 64];
  const u16* gB = B + (size_t)(tile_n + srow) * K + schunk * 8;

  // A staging (AF32): thread covers source chunk tid&7 of rows (tid>>3)+32*s,
  // dest chunk = src ^ (row&7); row&7 invariant across the 4 sub-iters.
  const int arow = tid >> 3;
  const int ac8  = tid & 7;
  const int adst = ((ac8 ^ (arow & 7)) << 3);
  const float* gAf = (const float*)Araw + (size_t)(tile_m + arow) * K + ac8 * 8;
  u16* ldsAw = &As[arow * 64 + adst];
  // A staging (bf16 async path)
  u16* ldsA = &As[((tid >> 6) * 8) * 64];
  const u16* gA = (const u16*)Araw + (size_t)(tile_m + srow) * K + schunk * 8;

  f32x4 acc[4][4];
#pragma unroll
  for (int i = 0; i < 4; i++)
#pragma unroll
    for (int j = 0; j < 4; j++) acc[i][j] = (f32x4){0.f, 0.f, 0.f, 0.f};

  const int lrow = lane & 15;
  const int kq   = lane >> 4;

  for (int k0 = 0; k0 < K; k0 += 64) {
    __syncthreads();
    if (AF32) {
#pragma unroll
      for (int s5 = 0; s5 < 4; s5++) {
        const float* src = gAf + (size_t)(s5 * 32) * K + k0;
        float4 v0 = *(const float4*)src;
        float4 v1 = *(const float4*)(src + 4);
        ushort4 o0 = {f2bf(v0.x), f2bf(v0.y), f2bf(v0.z), f2bf(v0.w)};
        ushort4 o1 = {f2bf(v1.x), f2bf(v1.y), f2bf(v1.z), f2bf(v1.w)};
        u16* d = ldsAw + s5 * 32 * 64;
        *(ushort4*)d = o0;
        *(ushort4*)(d + 4) = o1;
      }
#pragma unroll
      for (int i = 0; i < 4; i++)
        async_load16(gB + (size_t)(i * 32) * K + k0, ldsB + i * 32 * 64);
    } else {
#pragma unroll
      for (int i = 0; i < 4; i++) {
        async_load16(gA + (size_t)(i * 32) * K + k0, ldsA + i * 32 * 64);
        async_load16(gB + (size_t)(i * 32) * K + k0, ldsB + i * 32 * 64);
      }
    }
    __builtin_amdgcn_s_waitcnt(0);  // contractual drain (LDS-DMA + A ds_writes)
    __syncthreads();

#pragma unroll
    for (int js = 0; js < 2; js++) {
      // fragment wants global chunk kq+4*js of its row; stored at chunk ^ (row&7);
      // row&7 == lane&7 for all fragment rows (row offsets are multiples of 16).
      const int cc = ((kq + 4 * js) ^ (lane & 7)) << 3;
      bf16x8 a[4], b[4];
#pragma unroll
      for (int i = 0; i < 4; i++)
        a[i] = *(const bf16x8*)&As[(wm + i * 16 + lrow) * 64 + cc];
#pragma unroll
      for (int j = 0; j < 4; j++)
        b[j] = *(const bf16x8*)&Bs[(wn + j * 16 + lrow) * 64 + cc];
#pragma unroll
      for (int i = 0; i < 4; i++)
#pragma unroll
        for (int j = 0; j < 4; j++)
          acc[i][j] = __builtin_amdgcn_mfma_f32_16x16x32_bf16(a[i], b[j], acc[i][j], 0, 0, 0);
    }
  }

  // C/D layout: col = lane&15, row = (lane>>4)*4 + r  [measured m89/m91]
  const int crow = (lane >> 4) << 2;
  const int ccol = lane & 15;
#pragma unroll
  for (int i = 0; i < 4; i++) {
#pragma unroll
    for (int j = 0; j < 4; j++) {
      const int gm = tile_m + wm + i * 16 + crow;
      const int gn = tile_n + wn + j * 16 + ccol;
      const float bv = bias[gn];
#pragma unroll
      for (int r = 0; r < 4; r++) {
        float v = acc[i][j][r] + bv;
        if (RELU) v = fmaxf(v, 0.f);
        if (OUTBF) ((u16*)Cout)[(size_t)(gm + r) * N + gn] = f2bf(v);
        else       ((float*)Cout)[(size_t)(gm + r) * N + gn] = v;
      }
    }
  }
}

// ---------------- scan: m_t = beta*m_{t-1} + q_t over T=2048, channels = B*H = 8192 ----
// q is bf16 [T][8192]. 64 segments of 32 t-steps.
#define NCH 8192
#define SEG 32
#define NSEG 64

// pass1: per-segment carries (fp32 Horner over bf16 q; no double quantization).
__global__ __launch_bounds__(256) void scan_carry(const uint2* __restrict__ qb,
                                                  float* __restrict__ carry,
                                                  const float* __restrict__ beta_arr) {
  int tid = blockIdx.x * 256 + threadIdx.x;  // [0, 64*2048)
  int seg = tid >> 11;
  int cq  = tid & 2047;                      // channel quad
  int h0  = (cq * 4) & 1023;
  float b0 = beta_arr[h0], b1 = beta_arr[h0 + 1], b2 = beta_arr[h0 + 2], b3 = beta_arr[h0 + 3];
  const uint2* p = qb + (size_t)seg * SEG * 2048 + cq;
  float m0 = 0.f, m1 = 0.f, m2 = 0.f, m3 = 0.f;
#pragma unroll 8
  for (int t = 0; t < SEG; t++) {
    uint2 v = p[(size_t)t * 2048];
    m0 = fmaf(b0, m0, bf2f(v.x & 0xffffu));
    m1 = fmaf(b1, m1, bf2f(v.x >> 16));
    m2 = fmaf(b2, m2, bf2f(v.y & 0xffffu));
    m3 = fmaf(b3, m3, bf2f(v.y >> 16));
  }
  *(float4*)&carry[(size_t)seg * NCH + cq * 4] = make_float4(m0, m1, m2, m3);
}

// pass2 (fused fold + rescan): F = Horner-fold of the seg upstream carries with
// ratio beta^32 (2 MB buffer, L2-resident), then rescan 32 q steps from m=F and
// emit bf16 m. seg is uniform per block (8 blocks per segment).
__global__ __launch_bounds__(256) void scan_fuse(const uint2* __restrict__ qb,
                                                 const float4* __restrict__ carry4,
                                                 const float* __restrict__ beta_arr,
                                                 uint2* __restrict__ mb) {
  const int tid = blockIdx.x * 256 + threadIdx.x;  // [0, 64*2048)
  const int seg = tid >> 11;
  const int cq  = tid & 2047;
  const int h0  = (cq * 4) & 1023;
  const float b0 = beta_arr[h0], b1 = beta_arr[h0 + 1];
  const float b2 = beta_arr[h0 + 2], b3 = beta_arr[h0 + 3];
  float s0 = b0, s1 = b1, s2 = b2, s3 = b3;
#pragma unroll
  for (int i = 0; i < 5; i++) { s0 *= s0; s1 *= s1; s2 *= s2; s3 *= s3; }  // beta^32
  float m0 = 0.f, m1 = 0.f, m2 = 0.f, m3 = 0.f;
  const float4* cp = carry4 + cq;
  for (int s = 0; s < seg; s++) {  // uniform per block
    float4 c = cp[(size_t)s * 2048];
    m0 = fmaf(s0, m0, c.x); m1 = fmaf(s1, m1, c.y);
    m2 = fmaf(s2, m2, c.z); m3 = fmaf(s3, m3, c.w);
  }
  const uint2* p = qb + (size_t)seg * SEG * 2048 + cq;
  uint2* o = mb + (size_t)seg * SEG * 2048 + cq;
#pragma unroll 8
  for (int t = 0; t < SEG; t++) {
    uint2 v = p[(size_t)t * 2048];
    m0 = fmaf(b0, m0, bf2f(v.x & 0xffffu));
    m1 = fmaf(b1, m1, bf2f(v.x >> 16));
    m2 = fmaf(b2, m2, bf2f(v.y & 0xffffu));
    m3 = fmaf(b3, m3, bf2f(v.y >> 16));
    uint2 w;
    w.x = (uint32_t)f2bf(m0) | ((uint32_t)f2bf(m1) << 16);
    w.y = (uint32_t)f2bf(m2) | ((uint32_t)f2bf(m3) << 16);
    o[(size_t)t * 2048] = w;
  }
}

extern "C" void kernel_launch(void* const* d_in, const int* in_sizes, int n_in,
                              void* d_out, int out_size, void* d_ws, size_t ws_size,
                              hipStream_t stream) {
  const float* x        = (const float*)d_in[0];
  const float* W_q      = (const float*)d_in[1];
  const float* b_q      = (const float*)d_in[2];
  const float* beta_raw = (const float*)d_in[3];
  const float* W_fc     = (const float*)d_in[4];
  const float* b_fc     = (const float*)d_in[5];

  const int H = 1024;
  const int M = 2048 * 8;              // T*B = 16384 rows
  const size_t MH = (size_t)M * H;     // 16.7M elements

  char* ws = (char*)d_ws;
  u16* q_bf    = (u16*)ws;  ws += MH * 2;                   // 32 MB
  u16* m_bf    = (u16*)ws;  ws += MH * 2;                   // 32 MB
  u16* wq_bf   = (u16*)ws;  ws += (size_t)H * H * 2;        // 2 MB
  u16* wfc_bf  = (u16*)ws;  ws += (size_t)H * H * 2;        // 2 MB
  float* beta  = (float*)ws; ws += 4096;
  float* carry = (float*)ws; ws += (size_t)NSEG * NCH * 4;  // 2 MB

  prep_w<<<512, 256, 0, stream>>>(W_q, W_fc, beta_raw, wq_bf, wfc_bf, beta);

  gemm_bt<0, 1, 1><<<1024, 256, 0, stream>>>(x, wq_bf, b_q, q_bf, M, H, H);

  scan_carry<<<NSEG * (NCH / 4) / 256, 256, 0, stream>>>((const uint2*)q_bf, carry, beta);
  scan_fuse<<<NSEG * (NCH / 4) / 256, 256, 0, stream>>>((const uint2*)q_bf,
                                                        (const float4*)carry, beta,
                                                        (uint2*)m_bf);

  gemm_bt<1, 0, 0><<<1024, 256, 0, stream>>>(m_bf, wfc_bf, b_fc, d_out, M, H, H);
}